// Round 8
// baseline (90.928 us; speedup 1.0000x reference)
//
#include <hip/hip_runtime.h>
#include <stdint.h>

// HierarchicalZ2_12Quantizer on MI355X (gfx950) — DMA-pipelined, store-unchained.
// tokens = 8*4096 = 32768, D = 1024
// R7 post-mortem: epilogue vmcnt chain waited on prior iteration's global
// stores (stores are vmcnt ops; they were OLDER than the frag loads the
// compiler must wait for). R8: stores issued LAST each iter (newest ops),
// tri-buffered xe with depth-2 prefetch, gate atomics moved after the loop,
// P stride 34, nontemporal out stores.
// codes from bit patterns: c[j][i] = ((j>>(n-1-i))&1)?+1:-1.

#define DM 1024
#define TPB 64
#define OUT_OFF ((size_t)33554432)  // 8*4096*1024
#define NTOK 32768
#define NSLOT 32
#define WSA_OFF 32768               // float offset of gate-acc in ws

typedef float f32x4 __attribute__((ext_vector_type(4)));
typedef short bf16x8 __attribute__((ext_vector_type(8)));

typedef const __attribute__((address_space(1))) unsigned int* gas1_t;
typedef __attribute__((address_space(3))) unsigned int* las3_t;

__device__ __forceinline__ void gl_lds16(const void* g, void* l){
  __builtin_amdgcn_global_load_lds((gas1_t)g, (las3_t)l, 16, 0, 0);
}

__device__ __forceinline__ short f2bf(float f){
  unsigned u = __builtin_bit_cast(unsigned, f);
  unsigned r = u + 0x7fffu + ((u >> 16) & 1u);   // round-to-nearest-even
  return (short)(r >> 16);
}

// soft_quantize over the 2^NB hypercube corners; z[NB] -> q[NB]
template<int NB>
__device__ __forceinline__ void softq(const float* z, float invt, float* q){
  constexpr int K = 1 << NB;
  float d[K];
  float dmin = 3.4e38f;
#pragma unroll
  for (int j = 0; j < K; ++j){
    float acc = 0.f;
#pragma unroll
    for (int i = 0; i < NB; ++i){
      float c = ((j >> (NB-1-i)) & 1) ? 1.f : -1.f;
      float t = z[i] - c;
      acc = fmaf(t, t, acc);
    }
    float dj = sqrtf(acc);
    d[j] = dj;
    dmin = fminf(dmin, dj);
  }
  float S = 0.f;
  float s1[NB];
#pragma unroll
  for (int i = 0; i < NB; ++i) s1[i] = 0.f;
#pragma unroll
  for (int j = 0; j < K; ++j){
    float wj = __expf((dmin - d[j]) * invt);
    S += wj;
#pragma unroll
    for (int i = 0; i < NB; ++i)
      if ((j >> (NB-1-i)) & 1) s1[i] += wj;   // compile-time bit -> no branch
  }
  float rS = 1.f / S;
#pragma unroll
  for (int i = 0; i < NB; ++i) q[i] = 2.f * s1[i] * rS - 1.f;  // (S1-S0)/S
}

// ---------------- pack: weights -> bf16 B-fragments in ws (once) ------------
// wsF[0..32768)      : W24 frags, 32 ksteps x 2 nfrags x 64 lanes x 8
// wsF[32768..57344)  : Wf compact frags, 64 dfrags x 48 lanes x 8 (k<24)
__global__ __launch_bounds__(256) void pack_kernel(
    const float* __restrict__ w_to_l1,  const float* __restrict__ w_to_l2,
    const float* __restrict__ w_to_l3u, const float* __restrict__ w_to_l3l,
    const float* __restrict__ w_gate,
    const float* __restrict__ w_from_l1, const float* __restrict__ w_from_l2,
    const float* __restrict__ w_from_l3,
    short* __restrict__ wsF, float* __restrict__ wsA)
{
  int base = blockIdx.x*4096 + threadIdx.x*16;
#pragma unroll
  for (int q = 0; q < 16; ++q){
    int e = base + q;
    float v;
    if (e < 32768){
      int s  = e >> 10;
      int nf = (e >> 9) & 1;
      int ll = (e >> 3) & 63;
      int j  = e & 7;
      int k  = s*32 + ((ll >> 4) << 3) + j;
      int n  = nf*16 + (ll & 15);
      if      (n < 3)  v = w_gate  [k*3 + n];
      else if (n < 6)  v = w_to_l1 [k*3 + (n-3)];
      else if (n < 12) v = w_to_l2 [k*6 + (n-6)];
      else if (n < 18) v = w_to_l3u[k*6 + (n-12)];
      else if (n < 24) v = w_to_l3l[k*6 + (n-18)];
      else             v = 0.f;
    } else {
      int e2  = e - 32768;
      int f   = e2 / 384;
      int rem = e2 - f*384;
      int ll  = rem >> 3;
      int j   = e2 & 7;
      int k   = ((ll >> 4) << 3) + j;      // 0..23
      int dd  = f*16 + (ll & 15);
      if      (k < 3)  v = w_from_l1[k*DM + dd];
      else if (k < 9)  v = w_from_l2[(k-3)*DM + dd];
      else if (k < 21) v = w_from_l3[(k-9)*DM + dd];
      else             v = 0.f;
    }
    wsF[e] = f2bf(v);
  }
  if (blockIdx.x == 0){
    wsA[threadIdx.x]       = 0.f;
    wsA[threadIdx.x + 256] = 0.f;
  }
}

// ---------------- fused: down + quantize + up + residual (DMA-staged) -------
__global__ __launch_bounds__(256, 2) void hq6_kernel(
    const float* __restrict__ x, const short* __restrict__ wsF,
    const float* __restrict__ b_gate,
    const float* __restrict__ t1p, const float* __restrict__ t2p, const float* __restrict__ t3p,
    const float* __restrict__ s1p, const float* __restrict__ s2p, const float* __restrict__ s3p,
    float* __restrict__ wsA, float* __restrict__ out)
{
  // LDS map (80576 B total, 2 blocks/CU):
  //  [0,65536)      down: xb[wv][buf][16][128] f32 (per-wave dbuf)
  //  [0,49152)      epi:  xe[wv][3][16][64]    f32 (per-wave tri-buffer)
  //  [49152,66560)  epi:  C[64][68] f32 (overlaps dead down tail)
  //  [66560,75264)  P[64][34] f32
  //  [75264,80384)  V16[64][40] bf16
  //  [80384,80576)  GS[64][3] f32
  __shared__ alignas(16) char smem[80576];
  float* C   = reinterpret_cast<float*>(smem + 49152);
  float* P   = reinterpret_cast<float*>(smem + 66560);
  short* V16 = reinterpret_cast<short*>(smem + 75264);
  float* GS  = reinterpret_cast<float*>(smem + 80384);

  const int tid  = threadIdx.x;
  const int l    = tid & 63;
  const int wv   = tid >> 6;    // wave 0..3, owns tokens [wv*16, wv*16+16)
  const int kg   = l >> 4;
  const int ln16 = l & 15;
  const int tb   = blockIdx.x * TPB;

  // ================= down-proj: P = x @ W24 (full K per wave) ===============
  {
    f32x4 acc0 = {0.f,0.f,0.f,0.f}, acc1 = {0.f,0.f,0.f,0.f};
    const int lr0 = l >> 5;     // 0/1
    const int cbp = l & 31;     // 16B-block within 512B row
    // prologue: stage chunk 0 -> buf0 (8 x 1KB DMA per wave)
#pragma unroll
    for (int i = 0; i < 8; ++i){
      int lr = i*2 + lr0;
      gl_lds16(x + (size_t)(tb + wv*16 + lr)*DM + (cbp ^ (lr & 7))*4,
               smem + wv*16384 + i*1024 + l*16);
    }
#pragma unroll
    for (int t = 0; t < 8; ++t){
      const int buf = t & 1;
      // B-frags FIRST (older than next stage -> vmcnt(8) covers them)
      bf16x8 bfr[8];
#pragma unroll
      for (int s2 = 0; s2 < 8; ++s2)
        bfr[s2] = *reinterpret_cast<const bf16x8*>(&wsF[(t*8 + s2)*512 + l*8]);
      __builtin_amdgcn_sched_barrier(0);
      if (t < 7){
#pragma unroll
        for (int i = 0; i < 8; ++i){
          int lr = i*2 + lr0;
          gl_lds16(x + (size_t)(tb + wv*16 + lr)*DM + (t+1)*128 + (cbp ^ (lr & 7))*4,
                   smem + wv*16384 + (buf^1)*8192 + i*1024 + l*16);
        }
        asm volatile("s_waitcnt vmcnt(8)" ::: "memory");
      } else {
        asm volatile("s_waitcnt vmcnt(0)" ::: "memory");
      }
      const char* abase = smem + wv*16384 + buf*8192 + ln16*512;
#pragma unroll
      for (int s = 0; s < 4; ++s){
        float4 xa = *reinterpret_cast<const float4*>(abase + ((s*8 + kg*2 + 0) ^ (ln16 & 7))*16);
        float4 xb = *reinterpret_cast<const float4*>(abase + ((s*8 + kg*2 + 1) ^ (ln16 & 7))*16);
        bf16x8 af;
        af[0]=f2bf(xa.x); af[1]=f2bf(xa.y); af[2]=f2bf(xa.z); af[3]=f2bf(xa.w);
        af[4]=f2bf(xb.x); af[5]=f2bf(xb.y); af[6]=f2bf(xb.z); af[7]=f2bf(xb.w);
        acc0 = __builtin_amdgcn_mfma_f32_16x16x32_bf16(af, bfr[s*2+0], acc0, 0, 0, 0);
        acc1 = __builtin_amdgcn_mfma_f32_16x16x32_bf16(af, bfr[s*2+1], acc1, 0, 0, 0);
      }
    }
#pragma unroll
    for (int r = 0; r < 4; ++r){      // D: col = l&15, row = kg*4 + r
      int row = wv*16 + kg*4 + r;
      P[row*34 + ln16]      = acc0[r];
      P[row*34 + 16 + ln16] = acc1[r];
    }
  }
  __syncthreads();   // P complete; ALL down x-buffers dead

  // ---- epilogue prologue (issue order matters: DMA(0), bw(0), DMA(1)) ------
  const short* wsFC = wsF + 32768;
  bf16x8 bwc0={0,0,0,0,0,0,0,0}, bwc1=bwc0, bwc2=bwc0, bwc3=bwc0;
  {
#pragma unroll
    for (int j = 0; j < 4; ++j){     // DMA chunk 0 -> buf 0
      int lr = j*4 + (l >> 4);
      gl_lds16(x + (size_t)(tb + wv*16 + lr)*DM + ((l & 15) ^ (lr & 7))*4,
               smem + wv*12288 + j*1024 + l*16);
    }
    if (kg < 3){                     // bw frags for chunk 0
      bwc0 = *reinterpret_cast<const bf16x8*>(&wsFC[(0*4+0)*384 + l*8]);
      bwc1 = *reinterpret_cast<const bf16x8*>(&wsFC[(0*4+1)*384 + l*8]);
      bwc2 = *reinterpret_cast<const bf16x8*>(&wsFC[(0*4+2)*384 + l*8]);
      bwc3 = *reinterpret_cast<const bf16x8*>(&wsFC[(0*4+3)*384 + l*8]);
    }
#pragma unroll
    for (int j = 0; j < 4; ++j){     // DMA chunk 1 -> buf 1
      int lr = j*4 + (l >> 4);
      gl_lds16(x + (size_t)(tb + wv*16 + lr)*DM + 64 + ((l & 15) ^ (lr & 7))*4,
               smem + wv*12288 + 4096 + j*1024 + l*16);
    }
  }

  // ================= quantize (NO vmem ops: gate sums stay in regs) =========
  float qv[6] = {0,0,0,0,0,0};
  float myscale = 0.f;
  float sg0 = 0.f, sg1 = 0.f, sg2 = 0.f;
  {
    const int t = l;
    const int base = (wv == 3) ? 0 : 6 + wv*6;
    float z[6];
#pragma unroll
    for (int i = 0; i < 6; ++i) z[i] = P[t*34 + base + i];
    if (wv == 3){
      float invt1 = 1.f / fminf(fmaxf(__expf(t1p[0]), 0.01f), 5.0f);
      float g0l = z[0] + b_gate[0];
      float g1l = z[1] + b_gate[1];
      float g2l = z[2] + b_gate[2];
      float m  = fmaxf(g0l, fmaxf(g1l, g2l));
      float e0 = __expf(g0l - m), e1 = __expf(g1l - m), e2 = __expf(g2l - m);
      float rs = 1.f / (e0 + e1 + e2);
      float g0 = e0*rs, g1 = e1*rs, g2 = e2*rs;
      GS[t*3+0] = g0 * s1p[0];
      GS[t*3+1] = g1 * s2p[0];
      GS[t*3+2] = g2 * s3p[0];
      myscale   = g0 * s1p[0];
      float z1[3] = {z[3], z[4], z[5]};
      softq<3>(z1, invt1, qv);
      sg0 = g0; sg1 = g1; sg2 = g2;
#pragma unroll
      for (int mm = 1; mm < 64; mm <<= 1){
        sg0 += __shfl_xor(sg0, mm, 64);
        sg1 += __shfl_xor(sg1, mm, 64);
        sg2 += __shfl_xor(sg2, mm, 64);
      }
    } else {
      float tl = (wv == 0) ? t2p[0] : t3p[0];
      float invt = 1.f / fminf(fmaxf(__expf(tl), 0.01f), 5.0f);
      softq<6>(z, invt, qv);
    }
  }
  __syncthreads();   // GS visible

  // V writes (gate-scaled bf16). cols: l1 0..2, l2 3..8, l3u 9..14, l3l 15..20
  {
    const int t = l;
    if (wv == 3){
#pragma unroll
      for (int i = 0; i < 3; ++i) V16[t*40 + i] = f2bf(myscale * qv[i]);
      V16[t*40 + 21] = 0; V16[t*40 + 22] = 0; V16[t*40 + 23] = 0;  // kg=2 tail
    } else {
      float sc = GS[t*3 + ((wv == 0) ? 1 : 2)];
      int voff = 3 + wv*6;
#pragma unroll
      for (int i = 0; i < 6; ++i) V16[t*40 + voff + i] = f2bf(sc * qv[i]);
    }
  }
  __syncthreads();   // V complete

  // ================= up-proj + residual, 16 col-chunks of 64 ================
  bf16x8 aV = {0,0,0,0,0,0,0,0};
  if (kg < 3)
    aV = *reinterpret_cast<const bf16x8*>(&V16[(wv*16 + ln16)*40 + kg*8]);
  const f32x4 z4 = {0.f,0.f,0.f,0.f};
  const int rl = l >> 2;        // row within wave's 16
  const int cs = l & 3;         // col-seg

#pragma unroll
  for (int c = 0; c < 16; ++c){
    // xe(c) + bw(c) ready; stores/prefetch stay in flight (newest ops)
    if (c == 0 || c == 15) asm volatile("s_waitcnt vmcnt(4)" ::: "memory");
    else                   asm volatile("s_waitcnt vmcnt(8)" ::: "memory");
    __builtin_amdgcn_sched_barrier(0);
    // MFMA -> C (wave-local rows)
    {
      f32x4 d0 = __builtin_amdgcn_mfma_f32_16x16x32_bf16(aV, bwc0, z4, 0, 0, 0);
      f32x4 d1 = __builtin_amdgcn_mfma_f32_16x16x32_bf16(aV, bwc1, z4, 0, 0, 0);
      f32x4 d2 = __builtin_amdgcn_mfma_f32_16x16x32_bf16(aV, bwc2, z4, 0, 0, 0);
      f32x4 d3 = __builtin_amdgcn_mfma_f32_16x16x32_bf16(aV, bwc3, z4, 0, 0, 0);
#pragma unroll
      for (int r = 0; r < 4; ++r){
        int rowb = (wv*16 + kg*4 + r)*68;
        C[rowb +  0 + ln16] = d0[r];
        C[rowb + 16 + ln16] = d1[r];
        C[rowb + 32 + ln16] = d2[r];
        C[rowb + 48 + ln16] = d3[r];
      }
    }
    __builtin_amdgcn_sched_barrier(0);
    // next bw frags (issued BEFORE this chunk's stores -> no store chaining)
    bf16x8 bwn0 = bwc0, bwn1 = bwc1, bwn2 = bwc2, bwn3 = bwc3;
    if (c < 15 && kg < 3){
      bwn0 = *reinterpret_cast<const bf16x8*>(&wsFC[((c+1)*4+0)*384 + l*8]);
      bwn1 = *reinterpret_cast<const bf16x8*>(&wsFC[((c+1)*4+1)*384 + l*8]);
      bwn2 = *reinterpret_cast<const bf16x8*>(&wsFC[((c+1)*4+2)*384 + l*8]);
      bwn3 = *reinterpret_cast<const bf16x8*>(&wsFC[((c+1)*4+3)*384 + l*8]);
    }
    __builtin_amdgcn_sched_barrier(0);
    if (c < 14){                      // depth-2 prefetch into buf (c+2)%3
#pragma unroll
      for (int j = 0; j < 4; ++j){
        int lr = j*4 + (l >> 4);
        gl_lds16(x + (size_t)(tb + wv*16 + lr)*DM + (c+2)*64 + ((l & 15) ^ (lr & 7))*4,
                 smem + wv*12288 + ((c+2)%3)*4096 + j*1024 + l*16);
      }
    }
    __builtin_amdgcn_sched_barrier(0);
    asm volatile("s_waitcnt lgkmcnt(0)" ::: "memory");
    __builtin_amdgcn_sched_barrier(0);
    // residual pass (wave-local rows, 64B-run coalesced nt stores) — LAST
#pragma unroll
    for (int q = 0; q < 4; ++q){
      int bi = cs + 4*q;
      f32x4 xv = *reinterpret_cast<const f32x4*>(
          smem + wv*12288 + (c%3)*4096 + rl*256 + ((bi ^ (rl & 7)))*16);
      f32x4 cv = *reinterpret_cast<const f32x4*>(&C[(wv*16 + rl)*68 + bi*4]);
      f32x4 ov = xv + cv;
      __builtin_nontemporal_store(ov,
          reinterpret_cast<f32x4*>(&out[(size_t)(tb + wv*16 + rl)*DM + c*64 + bi*4]));
    }
    bwc0 = bwn0; bwc1 = bwn1; bwc2 = bwn2; bwc3 = bwn3;
  }

  // gate sums -> spread ws slots (after all counted waits; vmcnt-safe here)
  if (wv == 3 && l == 0){
    float* slot = wsA + (blockIdx.x & (NSLOT-1))*16;
    atomicAdd(slot + 0, sg0);
    atomicAdd(slot + 1, sg1);
    atomicAdd(slot + 2, sg2);
  }
}

// ---------------- finalize: reduce 32 gate slots -> out[OUT_OFF..+2] --------
__global__ void finalize_kernel(const float* __restrict__ wsA, float* __restrict__ out){
  if (threadIdx.x < 3){
    float s = 0.f;
    for (int j = 0; j < NSLOT; ++j) s += wsA[j*16 + threadIdx.x];
    out[OUT_OFF + threadIdx.x] = s * (1.f / (float)NTOK);
  }
}

extern "C" void kernel_launch(void* const* d_in, const int* in_sizes, int n_in,
                              void* d_out, int out_size, void* d_ws, size_t ws_size,
                              hipStream_t stream){
  (void)in_sizes; (void)n_in; (void)ws_size; (void)out_size;
  const float* x         = (const float*)d_in[0];
  // d_in[1] (codes_l1), d_in[2] (codes_l2) unused: corners derived from bits
  const float* w_to_l1   = (const float*)d_in[3];
  const float* w_from_l1 = (const float*)d_in[4];
  const float* w_to_l2   = (const float*)d_in[5];
  const float* w_from_l2 = (const float*)d_in[6];
  const float* w_to_l3u  = (const float*)d_in[7];
  const float* w_to_l3l  = (const float*)d_in[8];
  const float* w_from_l3 = (const float*)d_in[9];
  const float* w_gate    = (const float*)d_in[10];
  const float* b_gate    = (const float*)d_in[11];
  const float* t1 = (const float*)d_in[12];
  const float* t2 = (const float*)d_in[13];
  const float* t3 = (const float*)d_in[14];
  const float* s1 = (const float*)d_in[15];
  const float* s2 = (const float*)d_in[16];
  const float* s3 = (const float*)d_in[17];
  float* out  = (float*)d_out;
  short* wsF  = (short*)d_ws;                       // 57344 shorts of fragments
  float* wsA  = (float*)d_ws + WSA_OFF;             // 32 slots x 16 floats

  pack_kernel<<<dim3(14), dim3(256), 0, stream>>>(
      w_to_l1, w_to_l2, w_to_l3u, w_to_l3l, w_gate,
      w_from_l1, w_from_l2, w_from_l3, wsF, wsA);
  hq6_kernel<<<dim3(512), dim3(256), 0, stream>>>(
      x, wsF, b_gate, t1, t2, t3, s1, s2, s3, wsA, out);
  finalize_kernel<<<dim3(1), dim3(64), 0, stream>>>(wsA, out);
}

// Round 9
// 79.444 us; speedup vs baseline: 1.1446x; 1.1446x over previous
//
#include <hip/hip_runtime.h>
#include <stdint.h>

// HierarchicalZ2_12Quantizer on MI355X (gfx950) — DMA-pipelined, store-unchained,
// L2-merged stores.
// tokens = 8*4096 = 32768, D = 1024
// R8 post-mortem: nontemporal stores bypassed L2 write-merge -> WRITE_SIZE
// 131->170MB (+25us). R9 = R8 structure with normal float4 stores:
//   - epilogue issue order: wait -> MFMA -> C(LDS) -> bw(c+1) loads ->
//     DMA(c+2) -> lgkmcnt -> residual stores LAST (newest vmcnt ops).
//   - tri-buffered xe, depth-2 prefetch; gate atomics after the loop.
// codes from bit patterns: c[j][i] = ((j>>(n-1-i))&1)?+1:-1.

#define DM 1024
#define TPB 64
#define OUT_OFF ((size_t)33554432)  // 8*4096*1024
#define NTOK 32768
#define NSLOT 32
#define WSA_OFF 32768               // float offset of gate-acc in ws

typedef float f32x4 __attribute__((ext_vector_type(4)));
typedef short bf16x8 __attribute__((ext_vector_type(8)));

typedef const __attribute__((address_space(1))) unsigned int* gas1_t;
typedef __attribute__((address_space(3))) unsigned int* las3_t;

__device__ __forceinline__ void gl_lds16(const void* g, void* l){
  __builtin_amdgcn_global_load_lds((gas1_t)g, (las3_t)l, 16, 0, 0);
}

__device__ __forceinline__ short f2bf(float f){
  unsigned u = __builtin_bit_cast(unsigned, f);
  unsigned r = u + 0x7fffu + ((u >> 16) & 1u);   // round-to-nearest-even
  return (short)(r >> 16);
}

// soft_quantize over the 2^NB hypercube corners; z[NB] -> q[NB]
template<int NB>
__device__ __forceinline__ void softq(const float* z, float invt, float* q){
  constexpr int K = 1 << NB;
  float d[K];
  float dmin = 3.4e38f;
#pragma unroll
  for (int j = 0; j < K; ++j){
    float acc = 0.f;
#pragma unroll
    for (int i = 0; i < NB; ++i){
      float c = ((j >> (NB-1-i)) & 1) ? 1.f : -1.f;
      float t = z[i] - c;
      acc = fmaf(t, t, acc);
    }
    float dj = sqrtf(acc);
    d[j] = dj;
    dmin = fminf(dmin, dj);
  }
  float S = 0.f;
  float s1[NB];
#pragma unroll
  for (int i = 0; i < NB; ++i) s1[i] = 0.f;
#pragma unroll
  for (int j = 0; j < K; ++j){
    float wj = __expf((dmin - d[j]) * invt);
    S += wj;
#pragma unroll
    for (int i = 0; i < NB; ++i)
      if ((j >> (NB-1-i)) & 1) s1[i] += wj;   // compile-time bit -> no branch
  }
  float rS = 1.f / S;
#pragma unroll
  for (int i = 0; i < NB; ++i) q[i] = 2.f * s1[i] * rS - 1.f;  // (S1-S0)/S
}

// ---------------- pack: weights -> bf16 B-fragments in ws (once) ------------
// wsF[0..32768)      : W24 frags, 32 ksteps x 2 nfrags x 64 lanes x 8
// wsF[32768..57344)  : Wf compact frags, 64 dfrags x 48 lanes x 8 (k<24)
__global__ __launch_bounds__(256) void pack_kernel(
    const float* __restrict__ w_to_l1,  const float* __restrict__ w_to_l2,
    const float* __restrict__ w_to_l3u, const float* __restrict__ w_to_l3l,
    const float* __restrict__ w_gate,
    const float* __restrict__ w_from_l1, const float* __restrict__ w_from_l2,
    const float* __restrict__ w_from_l3,
    short* __restrict__ wsF, float* __restrict__ wsA)
{
  int base = blockIdx.x*4096 + threadIdx.x*16;
#pragma unroll
  for (int q = 0; q < 16; ++q){
    int e = base + q;
    float v;
    if (e < 32768){
      int s  = e >> 10;
      int nf = (e >> 9) & 1;
      int ll = (e >> 3) & 63;
      int j  = e & 7;
      int k  = s*32 + ((ll >> 4) << 3) + j;
      int n  = nf*16 + (ll & 15);
      if      (n < 3)  v = w_gate  [k*3 + n];
      else if (n < 6)  v = w_to_l1 [k*3 + (n-3)];
      else if (n < 12) v = w_to_l2 [k*6 + (n-6)];
      else if (n < 18) v = w_to_l3u[k*6 + (n-12)];
      else if (n < 24) v = w_to_l3l[k*6 + (n-18)];
      else             v = 0.f;
    } else {
      int e2  = e - 32768;
      int f   = e2 / 384;
      int rem = e2 - f*384;
      int ll  = rem >> 3;
      int j   = e2 & 7;
      int k   = ((ll >> 4) << 3) + j;      // 0..23
      int dd  = f*16 + (ll & 15);
      if      (k < 3)  v = w_from_l1[k*DM + dd];
      else if (k < 9)  v = w_from_l2[(k-3)*DM + dd];
      else if (k < 21) v = w_from_l3[(k-9)*DM + dd];
      else             v = 0.f;
    }
    wsF[e] = f2bf(v);
  }
  if (blockIdx.x == 0){
    wsA[threadIdx.x]       = 0.f;
    wsA[threadIdx.x + 256] = 0.f;
  }
}

// ---------------- fused: down + quantize + up + residual (DMA-staged) -------
__global__ __launch_bounds__(256, 2) void hq7_kernel(
    const float* __restrict__ x, const short* __restrict__ wsF,
    const float* __restrict__ b_gate,
    const float* __restrict__ t1p, const float* __restrict__ t2p, const float* __restrict__ t3p,
    const float* __restrict__ s1p, const float* __restrict__ s2p, const float* __restrict__ s3p,
    float* __restrict__ wsA, float* __restrict__ out)
{
  // LDS map (80576 B total, 2 blocks/CU):
  //  [0,65536)      down: xb[wv][buf][16][128] f32 (per-wave dbuf)
  //  [0,49152)      epi:  xe[wv][3][16][64]    f32 (per-wave tri-buffer)
  //  [49152,66560)  epi:  C[64][68] f32 (overlaps dead down tail)
  //  [66560,75264)  P[64][34] f32
  //  [75264,80384)  V16[64][40] bf16
  //  [80384,80576)  GS[64][3] f32
  __shared__ alignas(16) char smem[80576];
  float* C   = reinterpret_cast<float*>(smem + 49152);
  float* P   = reinterpret_cast<float*>(smem + 66560);
  short* V16 = reinterpret_cast<short*>(smem + 75264);
  float* GS  = reinterpret_cast<float*>(smem + 80384);

  const int tid  = threadIdx.x;
  const int l    = tid & 63;
  const int wv   = tid >> 6;    // wave 0..3, owns tokens [wv*16, wv*16+16)
  const int kg   = l >> 4;
  const int ln16 = l & 15;
  const int tb   = blockIdx.x * TPB;

  // ================= down-proj: P = x @ W24 (full K per wave) ===============
  {
    f32x4 acc0 = {0.f,0.f,0.f,0.f}, acc1 = {0.f,0.f,0.f,0.f};
    const int lr0 = l >> 5;     // 0/1
    const int cbp = l & 31;     // 16B-block within 512B row
    // prologue: stage chunk 0 -> buf0 (8 x 1KB DMA per wave)
#pragma unroll
    for (int i = 0; i < 8; ++i){
      int lr = i*2 + lr0;
      gl_lds16(x + (size_t)(tb + wv*16 + lr)*DM + (cbp ^ (lr & 7))*4,
               smem + wv*16384 + i*1024 + l*16);
    }
#pragma unroll
    for (int t = 0; t < 8; ++t){
      const int buf = t & 1;
      // B-frags FIRST (older than next stage -> vmcnt(8) covers them)
      bf16x8 bfr[8];
#pragma unroll
      for (int s2 = 0; s2 < 8; ++s2)
        bfr[s2] = *reinterpret_cast<const bf16x8*>(&wsF[(t*8 + s2)*512 + l*8]);
      __builtin_amdgcn_sched_barrier(0);
      if (t < 7){
#pragma unroll
        for (int i = 0; i < 8; ++i){
          int lr = i*2 + lr0;
          gl_lds16(x + (size_t)(tb + wv*16 + lr)*DM + (t+1)*128 + (cbp ^ (lr & 7))*4,
                   smem + wv*16384 + (buf^1)*8192 + i*1024 + l*16);
        }
        asm volatile("s_waitcnt vmcnt(8)" ::: "memory");
      } else {
        asm volatile("s_waitcnt vmcnt(0)" ::: "memory");
      }
      const char* abase = smem + wv*16384 + buf*8192 + ln16*512;
#pragma unroll
      for (int s = 0; s < 4; ++s){
        float4 xa = *reinterpret_cast<const float4*>(abase + ((s*8 + kg*2 + 0) ^ (ln16 & 7))*16);
        float4 xb = *reinterpret_cast<const float4*>(abase + ((s*8 + kg*2 + 1) ^ (ln16 & 7))*16);
        bf16x8 af;
        af[0]=f2bf(xa.x); af[1]=f2bf(xa.y); af[2]=f2bf(xa.z); af[3]=f2bf(xa.w);
        af[4]=f2bf(xb.x); af[5]=f2bf(xb.y); af[6]=f2bf(xb.z); af[7]=f2bf(xb.w);
        acc0 = __builtin_amdgcn_mfma_f32_16x16x32_bf16(af, bfr[s*2+0], acc0, 0, 0, 0);
        acc1 = __builtin_amdgcn_mfma_f32_16x16x32_bf16(af, bfr[s*2+1], acc1, 0, 0, 0);
      }
    }
#pragma unroll
    for (int r = 0; r < 4; ++r){      // D: col = l&15, row = kg*4 + r
      int row = wv*16 + kg*4 + r;
      P[row*34 + ln16]      = acc0[r];
      P[row*34 + 16 + ln16] = acc1[r];
    }
  }
  __syncthreads();   // P complete; ALL down x-buffers dead

  // ---- epilogue prologue (issue order matters: DMA(0), bw(0), DMA(1)) ------
  const short* wsFC = wsF + 32768;
  bf16x8 bwc0={0,0,0,0,0,0,0,0}, bwc1=bwc0, bwc2=bwc0, bwc3=bwc0;
  {
#pragma unroll
    for (int j = 0; j < 4; ++j){     // DMA chunk 0 -> buf 0
      int lr = j*4 + (l >> 4);
      gl_lds16(x + (size_t)(tb + wv*16 + lr)*DM + ((l & 15) ^ (lr & 7))*4,
               smem + wv*12288 + j*1024 + l*16);
    }
    if (kg < 3){                     // bw frags for chunk 0
      bwc0 = *reinterpret_cast<const bf16x8*>(&wsFC[(0*4+0)*384 + l*8]);
      bwc1 = *reinterpret_cast<const bf16x8*>(&wsFC[(0*4+1)*384 + l*8]);
      bwc2 = *reinterpret_cast<const bf16x8*>(&wsFC[(0*4+2)*384 + l*8]);
      bwc3 = *reinterpret_cast<const bf16x8*>(&wsFC[(0*4+3)*384 + l*8]);
    }
#pragma unroll
    for (int j = 0; j < 4; ++j){     // DMA chunk 1 -> buf 1
      int lr = j*4 + (l >> 4);
      gl_lds16(x + (size_t)(tb + wv*16 + lr)*DM + 64 + ((l & 15) ^ (lr & 7))*4,
               smem + wv*12288 + 4096 + j*1024 + l*16);
    }
  }

  // ================= quantize (NO vmem ops: gate sums stay in regs) =========
  float qv[6] = {0,0,0,0,0,0};
  float myscale = 0.f;
  float sg0 = 0.f, sg1 = 0.f, sg2 = 0.f;
  {
    const int t = l;
    const int base = (wv == 3) ? 0 : 6 + wv*6;
    float z[6];
#pragma unroll
    for (int i = 0; i < 6; ++i) z[i] = P[t*34 + base + i];
    if (wv == 3){
      float invt1 = 1.f / fminf(fmaxf(__expf(t1p[0]), 0.01f), 5.0f);
      float g0l = z[0] + b_gate[0];
      float g1l = z[1] + b_gate[1];
      float g2l = z[2] + b_gate[2];
      float m  = fmaxf(g0l, fmaxf(g1l, g2l));
      float e0 = __expf(g0l - m), e1 = __expf(g1l - m), e2 = __expf(g2l - m);
      float rs = 1.f / (e0 + e1 + e2);
      float g0 = e0*rs, g1 = e1*rs, g2 = e2*rs;
      GS[t*3+0] = g0 * s1p[0];
      GS[t*3+1] = g1 * s2p[0];
      GS[t*3+2] = g2 * s3p[0];
      myscale   = g0 * s1p[0];
      float z1[3] = {z[3], z[4], z[5]};
      softq<3>(z1, invt1, qv);
      sg0 = g0; sg1 = g1; sg2 = g2;
#pragma unroll
      for (int mm = 1; mm < 64; mm <<= 1){
        sg0 += __shfl_xor(sg0, mm, 64);
        sg1 += __shfl_xor(sg1, mm, 64);
        sg2 += __shfl_xor(sg2, mm, 64);
      }
    } else {
      float tl = (wv == 0) ? t2p[0] : t3p[0];
      float invt = 1.f / fminf(fmaxf(__expf(tl), 0.01f), 5.0f);
      softq<6>(z, invt, qv);
    }
  }
  __syncthreads();   // GS visible

  // V writes (gate-scaled bf16). cols: l1 0..2, l2 3..8, l3u 9..14, l3l 15..20
  {
    const int t = l;
    if (wv == 3){
#pragma unroll
      for (int i = 0; i < 3; ++i) V16[t*40 + i] = f2bf(myscale * qv[i]);
      V16[t*40 + 21] = 0; V16[t*40 + 22] = 0; V16[t*40 + 23] = 0;  // kg=2 tail
    } else {
      float sc = GS[t*3 + ((wv == 0) ? 1 : 2)];
      int voff = 3 + wv*6;
#pragma unroll
      for (int i = 0; i < 6; ++i) V16[t*40 + voff + i] = f2bf(sc * qv[i]);
    }
  }
  __syncthreads();   // V complete

  // ================= up-proj + residual, 16 col-chunks of 64 ================
  bf16x8 aV = {0,0,0,0,0,0,0,0};
  if (kg < 3)
    aV = *reinterpret_cast<const bf16x8*>(&V16[(wv*16 + ln16)*40 + kg*8]);
  const f32x4 z4 = {0.f,0.f,0.f,0.f};
  const int rl = l >> 2;        // row within wave's 16
  const int cs = l & 3;         // col-seg

#pragma unroll
  for (int c = 0; c < 16; ++c){
    // xe(c) + bw(c) ready; stores/prefetch stay in flight (newest ops)
    if (c == 0 || c == 15) asm volatile("s_waitcnt vmcnt(4)" ::: "memory");
    else                   asm volatile("s_waitcnt vmcnt(8)" ::: "memory");
    __builtin_amdgcn_sched_barrier(0);
    // MFMA -> C (wave-local rows)
    {
      f32x4 d0 = __builtin_amdgcn_mfma_f32_16x16x32_bf16(aV, bwc0, z4, 0, 0, 0);
      f32x4 d1 = __builtin_amdgcn_mfma_f32_16x16x32_bf16(aV, bwc1, z4, 0, 0, 0);
      f32x4 d2 = __builtin_amdgcn_mfma_f32_16x16x32_bf16(aV, bwc2, z4, 0, 0, 0);
      f32x4 d3 = __builtin_amdgcn_mfma_f32_16x16x32_bf16(aV, bwc3, z4, 0, 0, 0);
#pragma unroll
      for (int r = 0; r < 4; ++r){
        int rowb = (wv*16 + kg*4 + r)*68;
        C[rowb +  0 + ln16] = d0[r];
        C[rowb + 16 + ln16] = d1[r];
        C[rowb + 32 + ln16] = d2[r];
        C[rowb + 48 + ln16] = d3[r];
      }
    }
    __builtin_amdgcn_sched_barrier(0);
    // next bw frags (issued BEFORE this chunk's stores -> no store chaining)
    bf16x8 bwn0 = bwc0, bwn1 = bwc1, bwn2 = bwc2, bwn3 = bwc3;
    if (c < 15 && kg < 3){
      bwn0 = *reinterpret_cast<const bf16x8*>(&wsFC[((c+1)*4+0)*384 + l*8]);
      bwn1 = *reinterpret_cast<const bf16x8*>(&wsFC[((c+1)*4+1)*384 + l*8]);
      bwn2 = *reinterpret_cast<const bf16x8*>(&wsFC[((c+1)*4+2)*384 + l*8]);
      bwn3 = *reinterpret_cast<const bf16x8*>(&wsFC[((c+1)*4+3)*384 + l*8]);
    }
    __builtin_amdgcn_sched_barrier(0);
    if (c < 14){                      // depth-2 prefetch into buf (c+2)%3
#pragma unroll
      for (int j = 0; j < 4; ++j){
        int lr = j*4 + (l >> 4);
        gl_lds16(x + (size_t)(tb + wv*16 + lr)*DM + (c+2)*64 + ((l & 15) ^ (lr & 7))*4,
                 smem + wv*12288 + ((c+2)%3)*4096 + j*1024 + l*16);
      }
    }
    __builtin_amdgcn_sched_barrier(0);
    asm volatile("s_waitcnt lgkmcnt(0)" ::: "memory");
    __builtin_amdgcn_sched_barrier(0);
    // residual pass (wave-local rows, 64B-run coalesced stores, L2-merged) — LAST
#pragma unroll
    for (int q = 0; q < 4; ++q){
      int bi = cs + 4*q;
      f32x4 xv = *reinterpret_cast<const f32x4*>(
          smem + wv*12288 + (c%3)*4096 + rl*256 + ((bi ^ (rl & 7)))*16);
      f32x4 cv = *reinterpret_cast<const f32x4*>(&C[(wv*16 + rl)*68 + bi*4]);
      f32x4 ov = xv + cv;
      *reinterpret_cast<f32x4*>(&out[(size_t)(tb + wv*16 + rl)*DM + c*64 + bi*4]) = ov;
    }
    bwc0 = bwn0; bwc1 = bwn1; bwc2 = bwn2; bwc3 = bwn3;
  }

  // gate sums -> spread ws slots (after all counted waits; vmcnt-safe here)
  if (wv == 3 && l == 0){
    float* slot = wsA + (blockIdx.x & (NSLOT-1))*16;
    atomicAdd(slot + 0, sg0);
    atomicAdd(slot + 1, sg1);
    atomicAdd(slot + 2, sg2);
  }
}

// ---------------- finalize: reduce 32 gate slots -> out[OUT_OFF..+2] --------
__global__ void finalize_kernel(const float* __restrict__ wsA, float* __restrict__ out){
  if (threadIdx.x < 3){
    float s = 0.f;
    for (int j = 0; j < NSLOT; ++j) s += wsA[j*16 + threadIdx.x];
    out[OUT_OFF + threadIdx.x] = s * (1.f / (float)NTOK);
  }
}

extern "C" void kernel_launch(void* const* d_in, const int* in_sizes, int n_in,
                              void* d_out, int out_size, void* d_ws, size_t ws_size,
                              hipStream_t stream){
  (void)in_sizes; (void)n_in; (void)ws_size; (void)out_size;
  const float* x         = (const float*)d_in[0];
  // d_in[1] (codes_l1), d_in[2] (codes_l2) unused: corners derived from bits
  const float* w_to_l1   = (const float*)d_in[3];
  const float* w_from_l1 = (const float*)d_in[4];
  const float* w_to_l2   = (const float*)d_in[5];
  const float* w_from_l2 = (const float*)d_in[6];
  const float* w_to_l3u  = (const float*)d_in[7];
  const float* w_to_l3l  = (const float*)d_in[8];
  const float* w_from_l3 = (const float*)d_in[9];
  const float* w_gate    = (const float*)d_in[10];
  const float* b_gate    = (const float*)d_in[11];
  const float* t1 = (const float*)d_in[12];
  const float* t2 = (const float*)d_in[13];
  const float* t3 = (const float*)d_in[14];
  const float* s1 = (const float*)d_in[15];
  const float* s2 = (const float*)d_in[16];
  const float* s3 = (const float*)d_in[17];
  float* out  = (float*)d_out;
  short* wsF  = (short*)d_ws;                       // 57344 shorts of fragments
  float* wsA  = (float*)d_ws + WSA_OFF;             // 32 slots x 16 floats

  pack_kernel<<<dim3(14), dim3(256), 0, stream>>>(
      w_to_l1, w_to_l2, w_to_l3u, w_to_l3l, w_gate,
      w_from_l1, w_from_l2, w_from_l3, wsF, wsA);
  hq7_kernel<<<dim3(512), dim3(256), 0, stream>>>(
      x, wsF, b_gate, t1, t2, t3, s1, s2, s3, wsA, out);
  finalize_kernel<<<dim3(1), dim3(64), 0, stream>>>(wsA, out);
}